// Round 1
// baseline (1063.726 us; speedup 1.0000x reference)
//
#include <hip/hip_runtime.h>
#include <cstdint>
#include <cstddef>

#define RANK 10

typedef float f2_t __attribute__((ext_vector_type(2)));
typedef float f4_t __attribute__((ext_vector_type(4)));

// 32 rows/block, 2048 blocks, 256 threads (4 waves) -> 8 blocks/CU (was 4 at
// 64 rows/1024 blocks; latency-bound at 37% occupancy, VALUBusy 15%).
// LDS 20480 B/block = 8 * 20480 B = exactly 160 KiB/CU:
//   [0,4160)   x-tile 32 x 130 (pad +2; reused as rank-partials at a-boundary)
//   [4160,5120) ya[3][32][10] per-matrix reduced rank vectors (y product in slot 2)
// Wave w owns cols [w*32, w*32+32) of the 128-wide chunk; lane&31 = row,
// lane>>5 = k-half (16 cols each). Half-reduce via shfl_xor(32); cross-wave
// reduce done per-matrix at the a-boundary through LDS -- this frees the old
// res[3][10] registers so the kernel fits the 64-VGPR cap of 8 waves/SIMD.
__global__ __launch_bounds__(256, 8)
void cp_fusion_kernel(const float* __restrict__ x1, const float* __restrict__ x2,
                      const float* __restrict__ x3, const float* __restrict__ f1,
                      const float* __restrict__ f2, const float* __restrict__ f3,
                      const float* __restrict__ fo, float* __restrict__ out)
{
    __shared__ float lds[5120];
    const int tid  = threadIdx.x;
    const int lane = tid & 63;
    const int wid  = __builtin_amdgcn_readfirstlane(tid >> 6);
    const int row_base = blockIdx.x << 5;   // 2048 blocks * 32 rows

    const float* xs[3] = {x1, x2, x3};
    const float* fs[3] = {f1, f2, f3};
    const int    S [3] = {1024, 512, 768};
    const int    NC[3] = {8, 4, 6};

    const int rrow = lane & 31;                      // row this lane computes
    const int cb   = wid * 32 + ((lane >> 5) << 4);  // col-slice base in chunk

    f4_t fof[10];                                    // epilogue fo rows (loaded late)

    // ---- prologue: register-prefetch chunk 0 of x1 (8 x float2, coalesced:
    //      each wave reads one contiguous 512B row segment per i)
    f2_t xpre[8];
    #pragma unroll
    for (int i = 0; i < 8; ++i) {
        const int e   = tid + (i << 8);
        const int row = e >> 6;
        const int col = (e & 63) << 1;
        xpre[i] = *(const f2_t*)&x1[(size_t)(row_base + row) * 1024 + col];
    }

    #pragma unroll
    for (int a = 0; a < 3; ++a) {
        const float* __restrict__ xa = xs[a];
        const float* __restrict__ fa = fs[a];
        const int stride = S[a];
        const int nc = NC[a];

        float acc[RANK];
        #pragma unroll
        for (int r = 0; r < RANK; ++r) acc[r] = 0.f;

        #pragma unroll 1
        for (int c = 0; c < nc; ++c) {
            __syncthreads();               // tile region free (consumed/boundary done)
            // ---- drain prefetch regs into LDS
            #pragma unroll
            for (int i = 0; i < 8; ++i) {
                const int e   = tid + (i << 8);
                const int row = e >> 6;
                const int col = (e & 63) << 1;
                *(f2_t*)&lds[row * 130 + col] = xpre[i];
            }
            // ---- issue next tile's loads now; they fly during compute.
            //      At c == nc-1 prefetch the NEXT matrix's chunk 0 (kills the
            //      serial HBM bubble at each matrix transition).
            if (c + 1 < nc) {
                const int jb = (c + 1) << 7;
                #pragma unroll
                for (int i = 0; i < 8; ++i) {
                    const int e   = tid + (i << 8);
                    const int row = e >> 6;
                    const int col = (e & 63) << 1;
                    xpre[i] = *(const f2_t*)&xa[(size_t)(row_base + row) * stride + jb + col];
                }
            } else if (a < 2) {
                const float* __restrict__ xn = xs[a + 1];
                const int ns = S[a + 1];
                #pragma unroll
                for (int i = 0; i < 8; ++i) {
                    const int e   = tid + (i << 8);
                    const int row = e >> 6;
                    const int col = (e & 63) << 1;
                    xpre[i] = *(const f2_t*)&xn[(size_t)(row_base + row) * ns + col];
                }
            }
            __syncthreads();               // tile ready

            // ---- compute: 8 k-pairs, factors 5xfloat4 per pair (half-wave-
            //      uniform L1 hits); x from LDS (2-way bank alias = free).
            const float* __restrict__ fptr = fa + (size_t)((c << 7) + cb) * RANK;
            const float* __restrict__ xrow = &lds[rrow * 130 + cb];
            #pragma unroll
            for (int kp = 0; kp < 8; ++kp) {
                const f4_t b0 = *(const f4_t*)&fptr[kp * 20 +  0];
                const f4_t b1 = *(const f4_t*)&fptr[kp * 20 +  4];
                const f4_t b2 = *(const f4_t*)&fptr[kp * 20 +  8];
                const f4_t b3 = *(const f4_t*)&fptr[kp * 20 + 12];
                const f4_t b4 = *(const f4_t*)&fptr[kp * 20 + 16];
                const f2_t xv = *(const f2_t*)&xrow[kp << 1];
                // k0 = cb+2kp: ranks 0..9 = {b0.xyzw, b1.xyzw, b2.xy}
                acc[0] = fmaf(xv.x, b0.x, acc[0]);
                acc[1] = fmaf(xv.x, b0.y, acc[1]);
                acc[2] = fmaf(xv.x, b0.z, acc[2]);
                acc[3] = fmaf(xv.x, b0.w, acc[3]);
                acc[4] = fmaf(xv.x, b1.x, acc[4]);
                acc[5] = fmaf(xv.x, b1.y, acc[5]);
                acc[6] = fmaf(xv.x, b1.z, acc[6]);
                acc[7] = fmaf(xv.x, b1.w, acc[7]);
                acc[8] = fmaf(xv.x, b2.x, acc[8]);
                acc[9] = fmaf(xv.x, b2.y, acc[9]);
                // k1 = cb+2kp+1: ranks 0..9 = {b2.zw, b3.xyzw, b4.xyzw}
                acc[0] = fmaf(xv.y, b2.z, acc[0]);
                acc[1] = fmaf(xv.y, b2.w, acc[1]);
                acc[2] = fmaf(xv.y, b3.x, acc[2]);
                acc[3] = fmaf(xv.y, b3.y, acc[3]);
                acc[4] = fmaf(xv.y, b3.z, acc[4]);
                acc[5] = fmaf(xv.y, b3.w, acc[5]);
                acc[6] = fmaf(xv.y, b4.x, acc[6]);
                acc[7] = fmaf(xv.y, b4.y, acc[7]);
                acc[8] = fmaf(xv.y, b4.z, acc[8]);
                acc[9] = fmaf(xv.y, b4.w, acc[9]);
            }
        }

        // ---- a-boundary: fold k-halves, then cross-wave reduce through LDS.
        #pragma unroll
        for (int r = 0; r < RANK; ++r)
            acc[r] += __shfl_xor(acc[r], 32);

        if (a == 2) {                      // prefetch fo rows for the epilogue
            const int o0 = (tid & 127) << 2;
            const f4_t* __restrict__ fo4 = (const f4_t*)(fo + (size_t)o0 * RANK);
            #pragma unroll
            for (int p = 0; p < 10; ++p) fof[p] = fo4[p];
        }

        __syncthreads();                   // all waves done reading the tile
        if (lane < 32) {                   // partials into the (dead) tile region
            #pragma unroll
            for (int r = 0; r < RANK; ++r)
                lds[wid * 320 + rrow * 10 + r] = acc[r];
        }
        __syncthreads();
        if (tid < 32) {                    // combine 4 wave-slices -> ya[a]
            #pragma unroll
            for (int r = 0; r < RANK; ++r) {
                const float s = lds[        tid * 10 + r] + lds[320 + tid * 10 + r]
                              + lds[640 +  tid * 10 + r] + lds[960 + tid * 10 + r];
                if (a == 0)      lds[4160 + tid * 10 + r] = s;
                else if (a == 1) lds[4480 + tid * 10 + r] = s;
                else {
                    const float y0 = lds[4160 + tid * 10 + r];
                    const float y1 = lds[4480 + tid * 10 + r];
                    lds[4800 + tid * 10 + r] = y0 * y1 * s;   // y[row][r]
                }
            }
        }
        __syncthreads();                   // partials region free / y ready
    }

    // ---- epilogue: out[32][512] = y[32][10] @ fo^T ----
    const int o0 = (tid & 127) << 2;       // 4 output cols per thread
    const float* yb = lds + 4800;
    const int half = tid >> 7;             // waves 0,1 -> even rows; 2,3 -> odd
    #pragma unroll 2
    for (int i = 0; i < 16; ++i) {
        const int row = (i << 1) + half;   // wave-uniform -> y reads broadcast
        float yv[RANK];
        #pragma unroll
        for (int r = 0; r < RANK; ++r) yv[r] = yb[row * RANK + r];
        f4_t o = {0.f, 0.f, 0.f, 0.f};
        #pragma unroll
        for (int d = 0; d < 4; ++d) {
            float s = 0.f;
            #pragma unroll
            for (int r = 0; r < RANK; ++r) {
                const int q = d * RANK + r;
                s = fmaf(yv[r], fof[q >> 2][q & 3], s);
            }
            o[d] = s;
        }
        // streamed once -> nontemporal keeps x resident in L3 across dispatches
        __builtin_nontemporal_store(o, (f4_t*)&out[(size_t)(row_base + row) * 512 + o0]);
    }
}

extern "C" void kernel_launch(void* const* d_in, const int* in_sizes, int n_in,
                              void* d_out, int out_size, void* d_ws, size_t ws_size,
                              hipStream_t stream) {
    const float* x1 = (const float*)d_in[0];
    const float* x2 = (const float*)d_in[1];
    const float* x3 = (const float*)d_in[2];
    const float* f1 = (const float*)d_in[3];
    const float* f2 = (const float*)d_in[4];
    const float* f3 = (const float*)d_in[5];
    const float* fo = (const float*)d_in[6];
    float* out = (float*)d_out;
    (void)in_sizes; (void)n_in; (void)out_size; (void)d_ws; (void)ws_size;

    dim3 grid(2048), block(256);
    hipLaunchKernelGGL(cp_fusion_kernel, grid, block, 0, stream,
                       x1, x2, x3, f1, f2, f3, fo, out);
}

// Round 2
// 1016.855 us; speedup vs baseline: 1.0461x; 1.0461x over previous
//
#include <hip/hip_runtime.h>
#include <cstdint>
#include <cstddef>

#define RANK 10

typedef float f2_t __attribute__((ext_vector_type(2)));
typedef float f4_t __attribute__((ext_vector_type(4)));

// 32 rows/block, 2048 blocks, 256 threads (4 waves).
// LDS 20480 B/block -> 8 blocks/CU = exactly 160 KiB (the occupancy target).
// __launch_bounds__(256,4): cap 128 VGPRs -- NOT (256,8): the hard 64-cap made
// the allocator spill ~1.2KB/thread to scratch (round 1: FETCH 321->980 MB,
// VALUBusy 5%). The kernel naturally allocates ~60 VGPRs; at <=64 the HW
// schedules 8 blocks/CU on its own (launch_bounds min is a cap, not a ceiling
// on achieved occupancy).
//   LDS [0,4160)    x-tile 32 x 130 (pad +2; reused as rank-partials at a-boundary)
//   LDS [4160,5120) ya[3][32][10] per-matrix reduced rank rows (product in slot 2)
// Wave w owns cols [w*32, w*32+32); lane&31 = row, lane>>5 = k-half (16 cols).
// Half-reduce shfl_xor(32); cross-wave reduce per-matrix at the a-boundary
// through LDS (frees res[3][10] registers vs the 64-row version).
// fof[40] epilogue regs loaded only AFTER the a-loop so they never coexist
// with the main-loop working set.
__global__ __launch_bounds__(256, 4)
void cp_fusion_kernel(const float* __restrict__ x1, const float* __restrict__ x2,
                      const float* __restrict__ x3, const float* __restrict__ f1,
                      const float* __restrict__ f2, const float* __restrict__ f3,
                      const float* __restrict__ fo, float* __restrict__ out)
{
    __shared__ float lds[5120];
    const int tid  = threadIdx.x;
    const int lane = tid & 63;
    const int wid  = __builtin_amdgcn_readfirstlane(tid >> 6);
    const int row_base = blockIdx.x << 5;   // 2048 blocks * 32 rows

    const float* xs[3] = {x1, x2, x3};
    const float* fs[3] = {f1, f2, f3};
    const int    S [3] = {1024, 512, 768};
    const int    NC[3] = {8, 4, 6};

    const int rrow = lane & 31;                      // row this lane computes
    const int cb   = wid * 32 + ((lane >> 5) << 4);  // col-slice base in chunk

    // ---- prologue: register-prefetch chunk 0 of x1 (8 x float2, coalesced:
    //      each wave reads contiguous 512B row segments)
    f2_t xpre[8];
    #pragma unroll
    for (int i = 0; i < 8; ++i) {
        const int e   = tid + (i << 8);
        const int row = e >> 6;
        const int col = (e & 63) << 1;
        xpre[i] = *(const f2_t*)&x1[(size_t)(row_base + row) * 1024 + col];
    }

    #pragma unroll
    for (int a = 0; a < 3; ++a) {
        const float* __restrict__ xa = xs[a];
        const float* __restrict__ fa = fs[a];
        const int stride = S[a];
        const int nc = NC[a];

        float acc[RANK];
        #pragma unroll
        for (int r = 0; r < RANK; ++r) acc[r] = 0.f;

        #pragma unroll 1
        for (int c = 0; c < nc; ++c) {
            __syncthreads();               // tile region free (consumed/boundary done)
            // ---- drain prefetch regs into LDS
            #pragma unroll
            for (int i = 0; i < 8; ++i) {
                const int e   = tid + (i << 8);
                const int row = e >> 6;
                const int col = (e & 63) << 1;
                *(f2_t*)&lds[row * 130 + col] = xpre[i];
            }
            // ---- issue next tile's loads now; they fly during compute.
            //      At c == nc-1 prefetch the NEXT matrix's chunk 0 (kills the
            //      serial HBM bubble at each matrix transition).
            if (c + 1 < nc) {
                const int jb = (c + 1) << 7;
                #pragma unroll
                for (int i = 0; i < 8; ++i) {
                    const int e   = tid + (i << 8);
                    const int row = e >> 6;
                    const int col = (e & 63) << 1;
                    xpre[i] = *(const f2_t*)&xa[(size_t)(row_base + row) * stride + jb + col];
                }
            } else if (a < 2) {
                const float* __restrict__ xn = xs[a + 1];
                const int ns = S[a + 1];
                #pragma unroll
                for (int i = 0; i < 8; ++i) {
                    const int e   = tid + (i << 8);
                    const int row = e >> 6;
                    const int col = (e & 63) << 1;
                    xpre[i] = *(const f2_t*)&xn[(size_t)(row_base + row) * ns + col];
                }
            }
            __syncthreads();               // tile ready

            // ---- compute: 8 k-pairs, 5xfloat4 factor loads per pair
            //      (half-wave-uniform -> L1 broadcast); x from LDS (2-way
            //      bank alias = free).
            const float* __restrict__ fptr = fa + (size_t)((c << 7) + cb) * RANK;
            const float* __restrict__ xrow = &lds[rrow * 130 + cb];
            #pragma unroll
            for (int kp = 0; kp < 8; ++kp) {
                const f4_t b0 = *(const f4_t*)&fptr[kp * 20 +  0];
                const f4_t b1 = *(const f4_t*)&fptr[kp * 20 +  4];
                const f4_t b2 = *(const f4_t*)&fptr[kp * 20 +  8];
                const f4_t b3 = *(const f4_t*)&fptr[kp * 20 + 12];
                const f4_t b4 = *(const f4_t*)&fptr[kp * 20 + 16];
                const f2_t xv = *(const f2_t*)&xrow[kp << 1];
                // k0 = cb+2kp: ranks 0..9 = {b0.xyzw, b1.xyzw, b2.xy}
                acc[0] = fmaf(xv.x, b0.x, acc[0]);
                acc[1] = fmaf(xv.x, b0.y, acc[1]);
                acc[2] = fmaf(xv.x, b0.z, acc[2]);
                acc[3] = fmaf(xv.x, b0.w, acc[3]);
                acc[4] = fmaf(xv.x, b1.x, acc[4]);
                acc[5] = fmaf(xv.x, b1.y, acc[5]);
                acc[6] = fmaf(xv.x, b1.z, acc[6]);
                acc[7] = fmaf(xv.x, b1.w, acc[7]);
                acc[8] = fmaf(xv.x, b2.x, acc[8]);
                acc[9] = fmaf(xv.x, b2.y, acc[9]);
                // k1 = cb+2kp+1: ranks 0..9 = {b2.zw, b3.xyzw, b4.xyzw}
                acc[0] = fmaf(xv.y, b2.z, acc[0]);
                acc[1] = fmaf(xv.y, b2.w, acc[1]);
                acc[2] = fmaf(xv.y, b3.x, acc[2]);
                acc[3] = fmaf(xv.y, b3.y, acc[3]);
                acc[4] = fmaf(xv.y, b3.z, acc[4]);
                acc[5] = fmaf(xv.y, b3.w, acc[5]);
                acc[6] = fmaf(xv.y, b4.x, acc[6]);
                acc[7] = fmaf(xv.y, b4.y, acc[7]);
                acc[8] = fmaf(xv.y, b4.z, acc[8]);
                acc[9] = fmaf(xv.y, b4.w, acc[9]);
            }
        }

        // ---- a-boundary: fold k-halves, then cross-wave reduce through LDS.
        #pragma unroll
        for (int r = 0; r < RANK; ++r)
            acc[r] += __shfl_xor(acc[r], 32);

        __syncthreads();                   // all waves done reading the tile
        if (lane < 32) {                   // partials into the (dead) tile region
            #pragma unroll
            for (int r = 0; r < RANK; ++r)
                lds[wid * 320 + rrow * 10 + r] = acc[r];
        }
        __syncthreads();
        if (tid < 32) {                    // combine 4 wave-slices -> ya[a]
            #pragma unroll
            for (int r = 0; r < RANK; ++r) {
                const float s = lds[        tid * 10 + r] + lds[320 + tid * 10 + r]
                              + lds[640 +  tid * 10 + r] + lds[960 + tid * 10 + r];
                if (a == 0)      lds[4160 + tid * 10 + r] = s;
                else if (a == 1) lds[4480 + tid * 10 + r] = s;
                else {
                    const float y0 = lds[4160 + tid * 10 + r];
                    const float y1 = lds[4480 + tid * 10 + r];
                    lds[4800 + tid * 10 + r] = y0 * y1 * s;   // y[row][r]
                }
            }
        }
        __syncthreads();                   // partials region free / y ready
    }

    // ---- epilogue: out[32][512] = y[32][10] @ fo^T ----
    // fof loaded only now: its 40 regs never coexist with the main loop.
    const int o0 = (tid & 127) << 2;       // 4 output cols per thread
    const f4_t* __restrict__ fo4 = (const f4_t*)(fo + (size_t)o0 * RANK);
    f4_t fof[10];
    #pragma unroll
    for (int p = 0; p < 10; ++p) fof[p] = fo4[p];

    const float* yb = lds + 4800;
    const int half = tid >> 7;             // waves 0,1 -> even rows; 2,3 -> odd
    #pragma unroll 2
    for (int i = 0; i < 16; ++i) {
        const int row = (i << 1) + half;   // wave-uniform -> y reads broadcast
        float yv[RANK];
        #pragma unroll
        for (int r = 0; r < RANK; ++r) yv[r] = yb[row * RANK + r];
        f4_t o = {0.f, 0.f, 0.f, 0.f};
        #pragma unroll
        for (int d = 0; d < 4; ++d) {
            float s = 0.f;
            #pragma unroll
            for (int r = 0; r < RANK; ++r) {
                const int q = d * RANK + r;
                s = fmaf(yv[r], fof[q >> 2][q & 3], s);
            }
            o[d] = s;
        }
        // streamed once -> nontemporal keeps x resident in L3 across dispatches
        __builtin_nontemporal_store(o, (f4_t*)&out[(size_t)(row_base + row) * 512 + o0]);
    }
}

extern "C" void kernel_launch(void* const* d_in, const int* in_sizes, int n_in,
                              void* d_out, int out_size, void* d_ws, size_t ws_size,
                              hipStream_t stream) {
    const float* x1 = (const float*)d_in[0];
    const float* x2 = (const float*)d_in[1];
    const float* x3 = (const float*)d_in[2];
    const float* f1 = (const float*)d_in[3];
    const float* f2 = (const float*)d_in[4];
    const float* f3 = (const float*)d_in[5];
    const float* fo = (const float*)d_in[6];
    float* out = (float*)d_out;
    (void)in_sizes; (void)n_in; (void)out_size; (void)d_ws; (void)ws_size;

    dim3 grid(2048), block(256);
    hipLaunchKernelGGL(cp_fusion_kernel, grid, block, 0, stream,
                       x1, x2, x3, f1, f2, f3, fo, out);
}

// Round 3
// 598.423 us; speedup vs baseline: 1.7776x; 1.6992x over previous
//
#include <hip/hip_runtime.h>
#include <cstdint>
#include <cstddef>

#define RANK 10

typedef float f2_t __attribute__((ext_vector_type(2)));
typedef float f4_t __attribute__((ext_vector_type(4)));

// Direct global->LDS staging (no VGPR round-trip, nothing to spill):
__device__ __forceinline__ void gl16(const void* g, void* l) {
    __builtin_amdgcn_global_load_lds((const __attribute__((address_space(1))) void*)g,
                                     (__attribute__((address_space(3))) void*)l, 16, 0, 0);
}
__device__ __forceinline__ void gl4(const void* g, void* l) {
    __builtin_amdgcn_global_load_lds((const __attribute__((address_space(1))) void*)g,
                                     (__attribute__((address_space(3))) void*)l, 4, 0, 0);
}

// 32 rows/block, 2048 blocks, 256 threads (4 waves), 3 blocks/CU (LDS-limited).
// LDS (floats): XB[2] x-tiles 2*4096 @0, FB[2] factor chunks 2*1280 @8192,
//               YA 3*320 @10752. Total 11712 fl = 46848 B -> 3 blocks/CU,
//               so hipcc budgets ~170 VGPR: no spill (rounds 1-2 lesson: the
//               allocator targets LDS-implied occupancy and spills to hit it).
// Pipeline (m97/T3 pattern): issue chunk c+1 (6 gload_lds/wave: 4 x-tile 16B
// calls + 1KB + 256B factor calls) -> s_waitcnt vmcnt(6) [chunk c landed,
// c+1 keeps flying a full phase] -> raw s_barrier -> compute (pure LDS+FMA,
// factors from LDS so NO vmem op ever force-drains the prefetch FIFO) ->
// raw barrier. Never vmcnt(0) in the main loop.
// x LDS layout: linear [32][128] with source-side XOR swizzle
// (col16 ^= row&7; 16B-granule so gload_lds stays a contiguous-per-lane load);
// reads apply the same XOR -> 4-way residual bank alias on tiny volume.
__global__ __launch_bounds__(256, 3)
void cp_fusion_kernel(const float* __restrict__ x1, const float* __restrict__ x2,
                      const float* __restrict__ x3, const float* __restrict__ f1,
                      const float* __restrict__ f2, const float* __restrict__ f3,
                      const float* __restrict__ fo, float* __restrict__ out)
{
    __shared__ float lds[11712];
    const int tid  = threadIdx.x;
    const int lane = tid & 63;
    const int wid  = __builtin_amdgcn_readfirstlane(tid >> 6);
    const int row_base = blockIdx.x << 5;   // 2048 blocks * 32 rows

    const float* xs[3] = {x1, x2, x3};
    const float* fs[3] = {f1, f2, f3};
    const int    S [3] = {1024, 512, 768};
    const int    NC[3] = {8, 4, 6};

    const int rrow = lane & 31;                        // row this lane computes
    const int cbB  = (wid << 7) + ((lane >> 5) << 6);  // byte col base (col*4)
    const int xr   = (rrow & 7) << 4;                  // read-side XOR swizzle

    // ---- stage one chunk (x tile + factor chunk) into buffer `buf`
    auto stage_chunk = [&](const float* __restrict__ xa, int stride, int c,
                           const float* __restrict__ fa, int buf) {
        char* const lb = (char*)lds;
        #pragma unroll
        for (int j = 0; j < 4; ++j) {                  // 4 x 1KB wave-calls
            const int seg = (wid << 2) + j;            // 2 rows per seg
            const int row = (seg << 1) + (lane >> 5);
            const int csw = ((lane & 31) ^ (row & 7)) << 4;   // pre-swizzled src
            const char* g = (const char*)(xa + (size_t)(row_base + row) * stride
                                          + ((size_t)c << 7)) + csw;
            gl16(g, lb + (buf << 14) + (seg << 10));
        }
        // factors: chunk = fa[c*128 .. +128)[10] = 5120 contiguous bytes
        const char* fg = (const char*)(fa + (size_t)c * 1280);
        char* fb = lb + 32768 + buf * 5120;
        gl16(fg + (wid << 10) + (lane << 4), fb + (wid << 10));          // 4x1KB
        gl4 (fg + 4096 + (wid << 8) + (lane << 2), fb + 4096 + (wid << 8)); // 4x256B
    };

    stage_chunk(x1, 1024, 0, f1, 0);       // prologue: chunk 0 of matrix 0
    int cur = 0;

    #pragma unroll
    for (int a = 0; a < 3; ++a) {
        const float* __restrict__ xa = xs[a];
        const float* __restrict__ fa = fs[a];
        const int stride = S[a];
        const int nc = NC[a];

        float acc[RANK];
        #pragma unroll
        for (int r = 0; r < RANK; ++r) acc[r] = 0.f;

        #pragma unroll 1
        for (int c = 0; c < nc; ++c) {
            // ---- issue next chunk (or next matrix's chunk 0) into buf cur^1
            if (c + 1 < nc)      stage_chunk(xa, stride, c + 1, fa, cur ^ 1);
            else if (a < 2)      stage_chunk(xs[a + 1], S[a + 1], 0, fs[a + 1], cur ^ 1);

            // ---- chunk c landed (own 6 oldest); keep c+1's 6 in flight
            if (a == 2 && c == nc - 1) { asm volatile("s_waitcnt vmcnt(0)" ::: "memory"); }
            else                       { asm volatile("s_waitcnt vmcnt(6)" ::: "memory"); }
            __builtin_amdgcn_s_barrier();              // all waves' c-loads landed
            __builtin_amdgcn_sched_barrier(0);         // no ds_read hoisting (rule 18)

            // ---- compute: 8 k-pairs, factors broadcast from LDS (lgkmcnt only)
            const char* xb = (const char*)lds + (cur << 14) + (rrow << 9);
            const char* fb = (const char*)lds + 32768 + cur * 5120 + cbB * 10;
            #pragma unroll
            for (int kp = 0; kp < 8; ++kp) {
                const f2_t xv = *(const f2_t*)(xb + ((cbB + (kp << 3)) ^ xr));
                const f4_t b0 = *(const f4_t*)(fb + kp * 80 +  0);
                const f4_t b1 = *(const f4_t*)(fb + kp * 80 + 16);
                const f4_t b2 = *(const f4_t*)(fb + kp * 80 + 32);
                const f4_t b3 = *(const f4_t*)(fb + kp * 80 + 48);
                const f4_t b4 = *(const f4_t*)(fb + kp * 80 + 64);
                // k0: ranks 0..9 = {b0.xyzw, b1.xyzw, b2.xy}
                acc[0] = fmaf(xv.x, b0.x, acc[0]);
                acc[1] = fmaf(xv.x, b0.y, acc[1]);
                acc[2] = fmaf(xv.x, b0.z, acc[2]);
                acc[3] = fmaf(xv.x, b0.w, acc[3]);
                acc[4] = fmaf(xv.x, b1.x, acc[4]);
                acc[5] = fmaf(xv.x, b1.y, acc[5]);
                acc[6] = fmaf(xv.x, b1.z, acc[6]);
                acc[7] = fmaf(xv.x, b1.w, acc[7]);
                acc[8] = fmaf(xv.x, b2.x, acc[8]);
                acc[9] = fmaf(xv.x, b2.y, acc[9]);
                // k1: ranks 0..9 = {b2.zw, b3.xyzw, b4.xyzw}
                acc[0] = fmaf(xv.y, b2.z, acc[0]);
                acc[1] = fmaf(xv.y, b2.w, acc[1]);
                acc[2] = fmaf(xv.y, b3.x, acc[2]);
                acc[3] = fmaf(xv.y, b3.y, acc[3]);
                acc[4] = fmaf(xv.y, b3.z, acc[4]);
                acc[5] = fmaf(xv.y, b3.w, acc[5]);
                acc[6] = fmaf(xv.y, b4.x, acc[6]);
                acc[7] = fmaf(xv.y, b4.y, acc[7]);
                acc[8] = fmaf(xv.y, b4.z, acc[8]);
                acc[9] = fmaf(xv.y, b4.w, acc[9]);
            }
            __builtin_amdgcn_sched_barrier(0);
            __builtin_amdgcn_s_barrier();              // all done reading buf cur
            cur ^= 1;
        }

        // ---- a-boundary: fold k-halves, cross-wave reduce via just-freed tile.
        //      (next matrix's chunk 0 is still flying into XB(cur) -- we only
        //      touch XB(cur^1); no vmcnt waits here.)
        #pragma unroll
        for (int r = 0; r < RANK; ++r)
            acc[r] += __shfl_xor(acc[r], 32);

        float* pb = lds + ((cur ^ 1) << 12);           // dead x-tile as partials
        if (lane < 32) {
            #pragma unroll
            for (int r = 0; r < RANK; ++r)
                pb[wid * 320 + rrow * 10 + r] = acc[r];
        }
        asm volatile("s_waitcnt lgkmcnt(0)" ::: "memory");
        __builtin_amdgcn_s_barrier();
        __builtin_amdgcn_sched_barrier(0);
        if (tid < 32) {
            #pragma unroll
            for (int r = 0; r < RANK; ++r) {
                const float s = pb[      tid * 10 + r] + pb[320 + tid * 10 + r]
                              + pb[640 + tid * 10 + r] + pb[960 + tid * 10 + r];
                if (a == 0)      lds[10752 + tid * 10 + r] = s;
                else if (a == 1) lds[11072 + tid * 10 + r] = s;
                else {
                    const float y0 = lds[10752 + tid * 10 + r];
                    const float y1 = lds[11072 + tid * 10 + r];
                    lds[11392 + tid * 10 + r] = y0 * y1 * s;   // y[row][r]
                }
            }
        }
        asm volatile("s_waitcnt lgkmcnt(0)" ::: "memory");
        __builtin_amdgcn_s_barrier();
        __builtin_amdgcn_sched_barrier(0);
    }

    // ---- epilogue: out[32][512] = y[32][10] @ fo^T ----
    const int o0 = (tid & 127) << 2;       // 4 output cols per thread
    const f4_t* __restrict__ fo4 = (const f4_t*)(fo + (size_t)o0 * RANK);
    f4_t fof[10];
    #pragma unroll
    for (int p = 0; p < 10; ++p) fof[p] = fo4[p];

    const float* yb = lds + 11392;
    const int half = tid >> 7;             // waves 0,1 -> even rows; 2,3 -> odd
    #pragma unroll 2
    for (int i = 0; i < 16; ++i) {
        const int row = (i << 1) + half;   // wave-uniform -> y reads broadcast
        float yv[RANK];
        #pragma unroll
        for (int r = 0; r < RANK; ++r) yv[r] = yb[row * RANK + r];
        f4_t o = {0.f, 0.f, 0.f, 0.f};
        #pragma unroll
        for (int d = 0; d < 4; ++d) {
            float s = 0.f;
            #pragma unroll
            for (int r = 0; r < RANK; ++r) {
                const int q = d * RANK + r;
                s = fmaf(yv[r], fof[q >> 2][q & 3], s);
            }
            o[d] = s;
        }
        // streamed once -> nontemporal keeps x resident in L3 across dispatches
        __builtin_nontemporal_store(o, (f4_t*)&out[(size_t)(row_base + row) * 512 + o0]);
    }
}

extern "C" void kernel_launch(void* const* d_in, const int* in_sizes, int n_in,
                              void* d_out, int out_size, void* d_ws, size_t ws_size,
                              hipStream_t stream) {
    const float* x1 = (const float*)d_in[0];
    const float* x2 = (const float*)d_in[1];
    const float* x3 = (const float*)d_in[2];
    const float* f1 = (const float*)d_in[3];
    const float* f2 = (const float*)d_in[4];
    const float* f3 = (const float*)d_in[5];
    const float* fo = (const float*)d_in[6];
    float* out = (float*)d_out;
    (void)in_sizes; (void)n_in; (void)out_size; (void)d_ws; (void)ws_size;

    dim3 grid(2048), block(256);
    hipLaunchKernelGGL(cp_fusion_kernel, grid, block, 0, stream,
                       x1, x2, x3, f1, f2, f3, fo, out);
}